// Round 4
// baseline (1681.932 us; speedup 1.0000x reference)
//
#include <hip/hip_runtime.h>
#include <hip/hip_bf16.h>

// ---------------------------------------------------------------------------
// PointPillars encoder, fp32 reference-exact path.
// R3/R4: point stage atomics-free (scatter to slab + per-cell wave MLP).
//     R2 baseline: 11.3M device atomics -> 352 MB fabric RMW -> 480 us.
// Convs unchanged pending counters.
// ---------------------------------------------------------------------------

#define NXG 256
#define NYG 256

__global__ __launch_bounds__(256) void repack_w(const float* __restrict__ src,
                                                float* __restrict__ dst,
                                                int Cin, int Cout) {
    // src OIHW [co][ci][ky][kx] -> dst [t][ci][co], t = ky*3+kx
    int i = blockIdx.x * 256 + threadIdx.x;
    int total = Cout * Cin * 9;
    if (i >= total) return;
    int co = i / (Cin * 9);
    int r  = i - co * (Cin * 9);
    int ci = r / 9;
    int t  = r - ci * 9;
    dst[(t * Cin + ci) * Cout + co] = src[i];
}

__global__ void h2zero_k(const float* __restrict__ t1, const float* __restrict__ w2,
                         const float* __restrict__ s2, const float* __restrict__ t2,
                         float* __restrict__ h2z) {
    int co = threadIdx.x;  // 64 threads
    float acc = 0.f;
    for (int j = 0; j < 32; j++) {
        float h1 = fmaxf(t1[j], 0.f);
        acc += h1 * w2[j * 64 + co];
    }
    h2z[co] = fmaxf(acc * s2[co] + t2[co], 0.f);
}

// Pass 1: bin points into dense slab [cell][32][8 floats]. Only atomic is the
// 4B slot counter (~200k small atomics ~ 6 MB fabric traffic).
__global__ __launch_bounds__(256) void scatter_pts(const float4* __restrict__ pts, int n,
                                                   int* __restrict__ cnt,
                                                   float* __restrict__ slab) {
    int i = blockIdx.x * 256 + threadIdx.x;
    if (i >= n) return;
    float4 p = pts[i];
    float x = p.x, y = p.y, z = p.z, inten = p.w;
    if (!(x >= -51.2f && x < 51.2f && y >= -51.2f && y < 51.2f)) return;
    // IEEE division to match reference floor((x - X_MIN)/X_RES) exactly.
    float qx = (x - (-51.2f)) / 0.4f;
    float qy = (y - (-51.2f)) / 0.4f;
    int xi = (int)floorf(qx); xi = xi < 0 ? 0 : (xi > 255 ? 255 : xi);
    int yi = (int)floorf(qy); yi = yi < 0 ? 0 : (yi > 255 ? 255 : yi);
    int cell = yi * NXG + xi;
    int slot = atomicAdd(&cnt[cell], 1);
    if (slot >= 32) return;  // P(cell>32 pts) ~ 1e-30 at lambda~2.6
    float cx = (float)xi * 0.4f + -51.0f;
    float cy = (float)yi * 0.4f + -51.0f;
    float4* d = (float4*)(slab + ((size_t)cell * 32 + slot) * 8);
    d[0] = make_float4(x, y, z, inten);
    d[1] = make_float4(x - cx, y - cy, z, 0.f);
}

// Pass 2: one wave per cell (4 cells / 256-thread block). Lane co in [0,64)
// holds w2 column in 32 VGPRs, loops over the cell's occupied slots computing
// the fused 7->32->64 MLP (w1/s1/t1 wave-uniform -> scalar loads), running max
// in a register. Seeds with h2z (zero-padded-slot value) when 0 < cnt < 32.
__global__ __launch_bounds__(256) void cell_mlp(
    const int* __restrict__ cnt, const float* __restrict__ slab,
    const float* __restrict__ w1, const float* __restrict__ s1, const float* __restrict__ t1,
    const float* __restrict__ w2, const float* __restrict__ s2, const float* __restrict__ t2,
    const float* __restrict__ h2z, float* __restrict__ desc) {
    int cell = blockIdx.x * 4 + (threadIdx.x >> 6);
    int co = threadIdx.x & 63;
    float w2c[32];
#pragma unroll
    for (int j = 0; j < 32; j++) w2c[j] = w2[j * 64 + co];  // coalesced
    int c = cnt[cell];
    c = c < 32 ? c : 32;
    float m = (c > 0 && c < 32) ? h2z[co] : 0.f;
    float bs = s2[co], bt = t2[co];
    for (int s = 0; s < c; s++) {
        const float4* f = (const float4*)(slab + ((size_t)cell * 32 + s) * 8);
        float4 a = f[0], b = f[1];  // wave-uniform address -> broadcast
        float acc = 0.f;
#pragma unroll
        for (int k = 0; k < 32; k++) {
            float v = a.x * w1[0 * 32 + k] + a.y * w1[1 * 32 + k] + a.z * w1[2 * 32 + k]
                    + a.w * w1[3 * 32 + k] + b.x * w1[4 * 32 + k] + b.y * w1[5 * 32 + k]
                    + b.z * w1[6 * 32 + k];
            v = fmaxf(v * s1[k] + t1[k], 0.f);
            acc += v * w2c[k];
        }
        float h2 = fmaxf(acc * bs + bt, 0.f);
        m = fmaxf(m, h2);
    }
    desc[(size_t)cell * 64 + co] = m;
}

// Direct 3x3 conv, NHWC activations. Block = 16x16 pixel tile, 32 couts.
// Input tile (18x18 x 32cin-chunk) staged in LDS; weights [t][ci][co] read
// wave-uniformly (scalar loads). Thread = 1 pixel, 32 fp32 accumulators.
template <int CIN, int COUT, bool NCHW_OUT>
__global__ __launch_bounds__(256) void conv3x3(const float* __restrict__ in,
                                               const float* __restrict__ wT,
                                               const float* __restrict__ bs,
                                               const float* __restrict__ bt,
                                               float* __restrict__ out) {
    __shared__ float lds[18 * 18 * 32];  // 41,472 B
    const int tid = threadIdx.x;
    const int bx = blockIdx.x, by = blockIdx.y;
    const int coBase = blockIdx.z * 32;
    const int px = tid & 15, py = tid >> 4;

    float acc[32];
#pragma unroll
    for (int k = 0; k < 32; k++) acc[k] = 0.f;

    for (int cc = 0; cc < CIN / 32; ++cc) {
        if (cc) __syncthreads();
        // stage 18x18 halo tile for this 32-cin chunk
        for (int i = tid; i < 18 * 18 * 8; i += 256) {
            int p = i >> 3, c4 = i & 7;
            int ty = p / 18, tx = p - ty * 18;
            int gy = by * 16 + ty - 1, gx = bx * 16 + tx - 1;
            float4 v = make_float4(0.f, 0.f, 0.f, 0.f);
            if (gy >= 0 && gy < NYG && gx >= 0 && gx < NXG)
                v = *(const float4*)&in[((size_t)(gy * NXG + gx)) * CIN + cc * 32 + c4 * 4];
            *(float4*)&lds[p * 32 + c4 * 4] = v;
        }
        __syncthreads();

#pragma unroll 1
        for (int t = 0; t < 9; ++t) {
            int ky = t / 3, kx = t - ky * 3;
            int base = ((py + ky) * 18 + (px + kx)) * 32;
            const float* w = wT + ((size_t)(t * CIN + cc * 32)) * COUT + coBase;
#pragma unroll
            for (int c4 = 0; c4 < 8; c4++) {
                float4 xv = *(const float4*)&lds[base + c4 * 4];
#pragma unroll
                for (int j = 0; j < 4; j++) {
                    float xs = (j == 0) ? xv.x : (j == 1) ? xv.y : (j == 2) ? xv.z : xv.w;
                    const float* wr = w + (size_t)(c4 * 4 + j) * COUT;
#pragma unroll
                    for (int co = 0; co < 32; co += 4) {
                        float4 wv = *(const float4*)&wr[co];
                        acc[co + 0] += xs * wv.x;
                        acc[co + 1] += xs * wv.y;
                        acc[co + 2] += xs * wv.z;
                        acc[co + 3] += xs * wv.w;
                    }
                }
            }
        }
    }

    int gy = by * 16 + py, gx = bx * 16 + px;
#pragma unroll
    for (int co = 0; co < 32; co++) {
        float v = fmaxf(acc[co] * bs[coBase + co] + bt[coBase + co], 0.f);
        if (NCHW_OUT)
            out[(size_t)(coBase + co) * (NXG * NYG) + gy * NXG + gx] = v;
        else
            out[((size_t)(gy * NXG + gx)) * COUT + coBase + co] = v;
    }
}

extern "C" void kernel_launch(void* const* d_in, const int* in_sizes, int n_in,
                              void* d_out, int out_size, void* d_ws, size_t ws_size,
                              hipStream_t stream) {
    const float* points = (const float*)d_in[0];
    const float* w1 = (const float*)d_in[1];
    const float* s1 = (const float*)d_in[2];
    const float* t1 = (const float*)d_in[3];
    const float* w2 = (const float*)d_in[4];
    const float* s2 = (const float*)d_in[5];
    const float* t2 = (const float*)d_in[6];
    const float* cw1a = (const float*)d_in[7];
    const float* cs1a = (const float*)d_in[8];
    const float* ct1a = (const float*)d_in[9];
    const float* cw1b = (const float*)d_in[10];
    const float* cs1b = (const float*)d_in[11];
    const float* ct1b = (const float*)d_in[12];
    const float* cw2a = (const float*)d_in[13];
    const float* cs2a = (const float*)d_in[14];
    const float* ct2a = (const float*)d_in[15];
    const float* cw2b = (const float*)d_in[16];
    const float* cs2b = (const float*)d_in[17];
    const float* ct2b = (const float*)d_in[18];
    int n = in_sizes[0] / 4;

    // Workspace layout (~82 MB total):
    //   [0,       256K)  cnt
    //   [256K,    ~1.6M) repacked weights + h2z
    //   [2M,      18M)   R0: desc / conv input, 64ch NHWC (16 MB)
    //   [18M,     50M)   R1: 128ch NHWC (32 MB)
    //   [50M,     82M)   R2: 128ch NHWC (32 MB)
    //   slab (64 MB, point stage only) aliases R1+R2 (dead until conv1a).
    char* ws = (char*)d_ws;
    int*   cnt  = (int*)ws;                      // 256 KB
    float* wT1a = (float*)(ws + 262144);         // 288 KB
    float* wT1b = (float*)(ws + 557056);         // 576 KB
    float* wT2a = (float*)(ws + 1146880);        // 288 KB
    float* wT2b = (float*)(ws + 1441792);        // 144 KB
    float* h2z  = (float*)(ws + 1589248);        // 256 B
    float* R0 = (float*)(ws + (2ull << 20));
    float* R1 = (float*)(ws + (2ull << 20) + (16ull << 20));
    float* R2 = (float*)(ws + (2ull << 20) + (48ull << 20));
    float* slab = R1;  // 65536*32*8 floats = 64 MB, spans R1+R2

    hipMemsetAsync(cnt, 0, 262144, stream);

    repack_w<<<(128 * 64 * 9 + 255) / 256, 256, 0, stream>>>(cw1a, wT1a, 64, 128);
    repack_w<<<(128 * 128 * 9 + 255) / 256, 256, 0, stream>>>(cw1b, wT1b, 128, 128);
    repack_w<<<(64 * 128 * 9 + 255) / 256, 256, 0, stream>>>(cw2a, wT2a, 128, 64);
    repack_w<<<(64 * 64 * 9 + 255) / 256, 256, 0, stream>>>(cw2b, wT2b, 64, 64);
    h2zero_k<<<1, 64, 0, stream>>>(t1, w2, s2, t2, h2z);

    scatter_pts<<<(n + 255) / 256, 256, 0, stream>>>((const float4*)points, n, cnt, slab);
    cell_mlp<<<65536 / 4, 256, 0, stream>>>(cnt, slab, w1, s1, t1, w2, s2, t2, h2z, R0);

    conv3x3<64, 128, false><<<dim3(16, 16, 4), 256, 0, stream>>>(R0, wT1a, cs1a, ct1a, R1);
    conv3x3<128, 128, false><<<dim3(16, 16, 4), 256, 0, stream>>>(R1, wT1b, cs1b, ct1b, R2);
    conv3x3<128, 64, false><<<dim3(16, 16, 2), 256, 0, stream>>>(R2, wT2a, cs2a, ct2a, R0);
    conv3x3<64, 64, true><<<dim3(16, 16, 2), 256, 0, stream>>>(R0, wT2b, cs2b, ct2b, (float*)d_out);
}

// Round 6
// 1252.117 us; speedup vs baseline: 1.3433x; 1.3433x over previous
//
#include <hip/hip_runtime.h>
#include <hip/hip_bf16.h>

// ---------------------------------------------------------------------------
// PointPillars encoder, fp32 reference-exact path.
// R6: fix R5 conv bug -- weight row must use UNSWIZZLED channel index
//     (swizzle stores channel c at LDS offset c^sw; reading offset ci0+j
//      yields channel c4*4+j, so weights index with c4*4+j, not ci0+j).
// Point stage: count/scan/place/point-parallel-MLP/coalesced-reduce (R5).
// ---------------------------------------------------------------------------

#define NXG 256
#define NYG 256

__global__ __launch_bounds__(256) void repack_w(const float* __restrict__ src,
                                                float* __restrict__ dst,
                                                int Cin, int Cout) {
    // src OIHW [co][ci][ky][kx] -> dst [t][ci][co], t = ky*3+kx
    int i = blockIdx.x * 256 + threadIdx.x;
    int total = Cout * Cin * 9;
    if (i >= total) return;
    int co = i / (Cin * 9);
    int r  = i - co * (Cin * 9);
    int ci = r / 9;
    int t  = r - ci * 9;
    dst[(t * Cin + ci) * Cout + co] = src[i];
}

__global__ void h2zero_k(const float* __restrict__ t1, const float* __restrict__ w2,
                         const float* __restrict__ s2, const float* __restrict__ t2,
                         float* __restrict__ h2z) {
    int co = threadIdx.x;  // 64 threads
    float acc = 0.f;
    for (int j = 0; j < 32; j++) {
        float h1 = fmaxf(t1[j], 0.f);
        acc += h1 * w2[j * 64 + co];
    }
    h2z[co] = fmaxf(acc * s2[co] + t2[co], 0.f);
}

// ---- point stage ----------------------------------------------------------

__global__ __launch_bounds__(256) void count_pts(const float4* __restrict__ pts, int n,
                                                 int* __restrict__ cnt,
                                                 int* __restrict__ cellof) {
    int i = blockIdx.x * 256 + threadIdx.x;
    if (i >= n) return;
    float4 p = pts[i];
    int cell = -1;
    if (p.x >= -51.2f && p.x < 51.2f && p.y >= -51.2f && p.y < 51.2f) {
        // IEEE division to match reference floor((x - X_MIN)/X_RES) exactly.
        float qx = (p.x + 51.2f) / 0.4f;
        float qy = (p.y + 51.2f) / 0.4f;
        int xi = (int)floorf(qx); xi = xi < 0 ? 0 : (xi > 255 ? 255 : xi);
        int yi = (int)floorf(qy); yi = yi < 0 ? 0 : (yi > 255 ? 255 : yi);
        cell = yi * NXG + xi;
        atomicAdd(&cnt[cell], 1);
    }
    cellof[i] = cell;
}

// Block-level Hillis-Steele scan over 256 ints. scnt = exclusive-in-block,
// bsum[b] = block total. Also zeroes the placement cursor array.
__global__ __launch_bounds__(256) void scan1(const int* __restrict__ cnt,
                                             int* __restrict__ scnt,
                                             int* __restrict__ bsum,
                                             int* __restrict__ cur) {
    __shared__ int sm[256];
    int b = blockIdx.x, t = threadIdx.x;
    int v = cnt[b * 256 + t];
    sm[t] = v;
    __syncthreads();
    for (int off = 1; off < 256; off <<= 1) {
        int x = (t >= off) ? sm[t - off] : 0;
        __syncthreads();
        sm[t] += x;
        __syncthreads();
    }
    scnt[b * 256 + t] = sm[t] - v;       // exclusive
    if (t == 255) bsum[b] = sm[t];
    cur[b * 256 + t] = 0;
}

__global__ __launch_bounds__(256) void scan2(const int* __restrict__ bsum,
                                             int* __restrict__ boff,
                                             int* __restrict__ dT) {
    __shared__ int sm[256];
    int t = threadIdx.x;
    int v = bsum[t];
    sm[t] = v;
    __syncthreads();
    for (int off = 1; off < 256; off <<= 1) {
        int x = (t >= off) ? sm[t - off] : 0;
        __syncthreads();
        sm[t] += x;
        __syncthreads();
    }
    boff[t] = sm[t] - v;                 // exclusive
    if (t == 255) dT[0] = sm[t];
}

__global__ __launch_bounds__(256) void place_pts(const float4* __restrict__ pts, int n,
                                                 const int* __restrict__ cellof,
                                                 const int* __restrict__ scnt,
                                                 const int* __restrict__ boff,
                                                 int* __restrict__ cur,
                                                 float* __restrict__ fcomp) {
    int i = blockIdx.x * 256 + threadIdx.x;
    if (i >= n) return;
    int cell = cellof[i];
    if (cell < 0) return;
    int slot = atomicAdd(&cur[cell], 1);
    if (slot >= 32) return;  // P(cell>32 pts) ~ 1e-30 at lambda~2.6
    int pos = boff[cell >> 8] + scnt[cell] + slot;
    float4 p = pts[i];
    int xi = cell & 255, yi = cell >> 8;
    float cx = (float)xi * 0.4f + -51.0f;
    float cy = (float)yi * 0.4f + -51.0f;
    float4* d = (float4*)(fcomp + (size_t)pos * 8);
    d[0] = make_float4(p.x, p.y, p.z, p.w);
    d[1] = make_float4(p.x - cx, p.y - cy, p.z, 0.f);
}

// Point-parallel fused 7->32->64 MLP over the compact point list.
__global__ __launch_bounds__(256) void mlp_pts(
    const float* __restrict__ fcomp, const int* __restrict__ dT,
    const float* __restrict__ w1, const float* __restrict__ s1, const float* __restrict__ t1,
    const float* __restrict__ w2, const float* __restrict__ s2, const float* __restrict__ t2,
    float* __restrict__ hcomp) {
    int i = blockIdx.x * 256 + threadIdx.x;
    if (i >= dT[0]) return;
    const float4* f = (const float4*)(fcomp + (size_t)i * 8);
    float4 a = f[0], b = f[1];
    float h1[32];
#pragma unroll
    for (int k = 0; k < 32; k++) {
        float v = a.x * w1[0 * 32 + k] + a.y * w1[1 * 32 + k] + a.z * w1[2 * 32 + k]
                + a.w * w1[3 * 32 + k] + b.x * w1[4 * 32 + k] + b.y * w1[5 * 32 + k]
                + b.z * w1[6 * 32 + k];
        h1[k] = fmaxf(v * s1[k] + t1[k], 0.f);
    }
    float acc[64];
#pragma unroll
    for (int c = 0; c < 64; c++) acc[c] = 0.f;
#pragma unroll
    for (int k = 0; k < 32; k++) {
        float hk = h1[k];
#pragma unroll
        for (int c4 = 0; c4 < 16; c4++) {
            float4 wv = *(const float4*)&w2[k * 64 + c4 * 4];
            acc[c4 * 4 + 0] += hk * wv.x;
            acc[c4 * 4 + 1] += hk * wv.y;
            acc[c4 * 4 + 2] += hk * wv.z;
            acc[c4 * 4 + 3] += hk * wv.w;
        }
    }
    float* o = hcomp + (size_t)i * 64;
#pragma unroll
    for (int c4 = 0; c4 < 16; c4++) {
        float4 ov;
        ov.x = fmaxf(acc[c4 * 4 + 0] * s2[c4 * 4 + 0] + t2[c4 * 4 + 0], 0.f);
        ov.y = fmaxf(acc[c4 * 4 + 1] * s2[c4 * 4 + 1] + t2[c4 * 4 + 1], 0.f);
        ov.z = fmaxf(acc[c4 * 4 + 2] * s2[c4 * 4 + 2] + t2[c4 * 4 + 2], 0.f);
        ov.w = fmaxf(acc[c4 * 4 + 3] * s2[c4 * 4 + 3] + t2[c4 * 4 + 3], 0.f);
        *(float4*)&o[c4 * 4] = ov;
    }
}

// Wave per cell, lane = cout. Coalesced 256B read per slot.
__global__ __launch_bounds__(256) void cell_reduce(
    const int* __restrict__ cnt, const int* __restrict__ scnt,
    const int* __restrict__ boff, const float* __restrict__ hcomp,
    const float* __restrict__ h2z, float* __restrict__ desc) {
    int cell = blockIdx.x * 4 + (threadIdx.x >> 6);
    int co = threadIdx.x & 63;
    int c = cnt[cell];
    int start = boff[cell >> 8] + scnt[cell];
    int cc = c < 32 ? c : 32;
    float m = (c > 0 && c < 32) ? h2z[co] : 0.f;
    const float* hp = hcomp + (size_t)start * 64 + co;
    for (int s = 0; s < cc; s++) m = fmaxf(m, hp[(size_t)s * 64]);
    desc[(size_t)cell * 64 + co] = m;
}

// ---- conv stack -----------------------------------------------------------
// Direct 3x3 conv, NHWC. Block = 16x16 pixels, 32 couts/thread. LDS tile is
// XOR-swizzled: channel c of pixel p lives at offset c ^ ((p&7)<<2) (sw hits
// bits 2-4 only, so each float4 quad stays contiguous). Spreads the 64 lanes
// of each ds_read_b128 across all 8 bank quads (old: all lanes on one quad).
// Weights index with the TRUE channel c4*4+j (R5 bug: used swizzled offset).
template <int CIN, int COUT, bool NCHW_OUT>
__global__ __launch_bounds__(256) void conv3x3(const float* __restrict__ in,
                                               const float* __restrict__ wT,
                                               const float* __restrict__ bs,
                                               const float* __restrict__ bt,
                                               float* __restrict__ out) {
    __shared__ float lds[18 * 18 * 32];  // 41,472 B
    const int tid = threadIdx.x;
    const int bx = blockIdx.x, by = blockIdx.y;
    const int coBase = blockIdx.z * 32;
    const int px = tid & 15, py = tid >> 4;

    float acc[32];
#pragma unroll
    for (int k = 0; k < 32; k++) acc[k] = 0.f;

    for (int cc = 0; cc < CIN / 32; ++cc) {
        if (cc) __syncthreads();
        // stage 18x18 halo tile for this 32-cin chunk (swizzled write)
        for (int i = tid; i < 18 * 18 * 8; i += 256) {
            int p = i >> 3, c4 = i & 7;
            int ty = p / 18, tx = p - ty * 18;
            int gy = by * 16 + ty - 1, gx = bx * 16 + tx - 1;
            float4 v = make_float4(0.f, 0.f, 0.f, 0.f);
            if (gy >= 0 && gy < NYG && gx >= 0 && gx < NXG)
                v = *(const float4*)&in[((size_t)(gy * NXG + gx)) * CIN + cc * 32 + c4 * 4];
            *(float4*)&lds[p * 32 + ((c4 * 4) ^ ((p & 7) << 2))] = v;
        }
        __syncthreads();

#pragma unroll 1
        for (int t = 0; t < 9; ++t) {
            int ky = t / 3, kx = t - ky * 3;
            int P = (py + ky) * 18 + (px + kx);
            int base = P * 32;
            int sw = (P & 7) << 2;
            const float* w = wT + ((size_t)(t * CIN + cc * 32)) * COUT + coBase;
#pragma unroll
            for (int c4 = 0; c4 < 8; c4++) {
                // LDS offset is swizzled; data there is channels c4*4..c4*4+3.
                float4 xv = *(const float4*)&lds[base + ((c4 * 4) ^ sw)];
#pragma unroll
                for (int j = 0; j < 4; j++) {
                    float xs = (j == 0) ? xv.x : (j == 1) ? xv.y : (j == 2) ? xv.z : xv.w;
                    const float* wr = w + (size_t)(c4 * 4 + j) * COUT;  // TRUE channel
#pragma unroll
                    for (int co = 0; co < 32; co += 4) {
                        float4 wv = *(const float4*)&wr[co];
                        acc[co + 0] += xs * wv.x;
                        acc[co + 1] += xs * wv.y;
                        acc[co + 2] += xs * wv.z;
                        acc[co + 3] += xs * wv.w;
                    }
                }
            }
        }
    }

    int gy = by * 16 + py, gx = bx * 16 + px;
#pragma unroll
    for (int co = 0; co < 32; co++) {
        float v = fmaxf(acc[co] * bs[coBase + co] + bt[coBase + co], 0.f);
        if (NCHW_OUT)
            out[(size_t)(coBase + co) * (NXG * NYG) + gy * NXG + gx] = v;
        else
            out[((size_t)(gy * NXG + gx)) * COUT + coBase + co] = v;
    }
}

extern "C" void kernel_launch(void* const* d_in, const int* in_sizes, int n_in,
                              void* d_out, int out_size, void* d_ws, size_t ws_size,
                              hipStream_t stream) {
    const float* points = (const float*)d_in[0];
    const float* w1 = (const float*)d_in[1];
    const float* s1 = (const float*)d_in[2];
    const float* t1 = (const float*)d_in[3];
    const float* w2 = (const float*)d_in[4];
    const float* s2 = (const float*)d_in[5];
    const float* t2 = (const float*)d_in[6];
    const float* cw1a = (const float*)d_in[7];
    const float* cs1a = (const float*)d_in[8];
    const float* ct1a = (const float*)d_in[9];
    const float* cw1b = (const float*)d_in[10];
    const float* cs1b = (const float*)d_in[11];
    const float* ct1b = (const float*)d_in[12];
    const float* cw2a = (const float*)d_in[13];
    const float* cs2a = (const float*)d_in[14];
    const float* ct2a = (const float*)d_in[15];
    const float* cw2b = (const float*)d_in[16];
    const float* cs2b = (const float*)d_in[17];
    const float* ct2b = (const float*)d_in[18];
    int n = in_sizes[0] / 4;

    // Workspace layout (92 MB; 98 MB proven OK in R2):
    //   0    cnt 256K | 256K scnt 256K | 512K cur 256K | 768K boff 4K
    //   772K dT 4K    | 776K h2z 4K    | 1M cellof 800K | 1.82M bsum 1K
    //   2M wT1a 288K | 2.5M wT1b 576K | 3.25M wT2a 288K | 3.75M wT2b 144K
    //   4M  fcomp 6.4M (dead after mlp_pts)
    //   12M R0 16M (desc / conv io)
    //   28M hcomp 51.2M -- aliases R1/R2 (dead before conv1a writes R1)
    //   28M R1 32M | 60M R2 32M
    char* ws = (char*)d_ws;
    int*   cnt    = (int*)(ws + 0);
    int*   scnt   = (int*)(ws + 262144);
    int*   cur    = (int*)(ws + 524288);
    int*   boff   = (int*)(ws + 786432);
    int*   dT     = (int*)(ws + 790528);
    float* h2z    = (float*)(ws + 794624);
    int*   cellof = (int*)(ws + (1ull << 20));
    int*   bsum   = (int*)(ws + (1ull << 20) + 819200);
    float* wT1a = (float*)(ws + 2097152);
    float* wT1b = (float*)(ws + 2621440);
    float* wT2a = (float*)(ws + 3407872);
    float* wT2b = (float*)(ws + 3932160);
    float* fcomp = (float*)(ws + (4ull << 20));
    float* R0    = (float*)(ws + (12ull << 20));
    float* hcomp = (float*)(ws + (28ull << 20));
    float* R1    = (float*)(ws + (28ull << 20));
    float* R2    = (float*)(ws + (60ull << 20));

    hipMemsetAsync(cnt, 0, 262144, stream);

    repack_w<<<(128 * 64 * 9 + 255) / 256, 256, 0, stream>>>(cw1a, wT1a, 64, 128);
    repack_w<<<(128 * 128 * 9 + 255) / 256, 256, 0, stream>>>(cw1b, wT1b, 128, 128);
    repack_w<<<(64 * 128 * 9 + 255) / 256, 256, 0, stream>>>(cw2a, wT2a, 128, 64);
    repack_w<<<(64 * 64 * 9 + 255) / 256, 256, 0, stream>>>(cw2b, wT2b, 64, 64);
    h2zero_k<<<1, 64, 0, stream>>>(t1, w2, s2, t2, h2z);

    count_pts<<<(n + 255) / 256, 256, 0, stream>>>((const float4*)points, n, cnt, cellof);
    scan1<<<256, 256, 0, stream>>>(cnt, scnt, bsum, cur);
    scan2<<<1, 256, 0, stream>>>(bsum, boff, dT);
    place_pts<<<(n + 255) / 256, 256, 0, stream>>>((const float4*)points, n, cellof,
                                                   scnt, boff, cur, fcomp);
    mlp_pts<<<(n + 255) / 256, 256, 0, stream>>>(fcomp, dT, w1, s1, t1, w2, s2, t2, hcomp);
    cell_reduce<<<65536 / 4, 256, 0, stream>>>(cnt, scnt, boff, hcomp, h2z, R0);

    conv3x3<64, 128, false><<<dim3(16, 16, 4), 256, 0, stream>>>(R0, wT1a, cs1a, ct1a, R1);
    conv3x3<128, 128, false><<<dim3(16, 16, 4), 256, 0, stream>>>(R1, wT1b, cs1b, ct1b, R2);
    conv3x3<128, 64, false><<<dim3(16, 16, 2), 256, 0, stream>>>(R2, wT2a, cs2a, ct2a, R0);
    conv3x3<64, 64, true><<<dim3(16, 16, 2), 256, 0, stream>>>(R0, wT2b, cs2b, ct2b, (float*)d_out);
}

// Round 7
// 434.443 us; speedup vs baseline: 3.8715x; 2.8821x over previous
//
#include <hip/hip_runtime.h>
#include <hip/hip_bf16.h>

// ---------------------------------------------------------------------------
// PointPillars encoder.
// R7: convs -> MFMA (bf16 hi/lo split, 3 MFMA terms: Ah*Wh + Ah*Wl + Al*Wh).
//     Exact to ~2^-17 per product; fp32 accumulate in AGPRs.
//     R6 VALU conv was weight-load latency-bound: VALUBusy 34%, MfmaUtil 0.
// Point stage (count/scan/place/point-MLP/reduce) unchanged except reduce
// now emits bf16 hi/lo planes feeding conv1a.
// ---------------------------------------------------------------------------

#define NXG 256
#define NYG 256

typedef unsigned short u16;
typedef unsigned int u32;
typedef __attribute__((ext_vector_type(8))) short sx8;   // 8 bf16 (4 VGPR)
typedef __attribute__((ext_vector_type(4))) float fx4;   // 4 f32
typedef __attribute__((ext_vector_type(4))) u32 ux4;     // 16B

// round-to-nearest-even fp32 -> bf16 bits
__device__ __forceinline__ u16 f2bf(float x) {
    u32 u = __float_as_uint(x);
    return (u16)((u + 0x7fffu + ((u >> 16) & 1u)) >> 16);
}

// ---- weight repack + split: OIHW fp32 -> [t][co][ci] bf16 hi/lo ----------
__global__ __launch_bounds__(256) void repack_wb(const float* __restrict__ src,
                                                 u16* __restrict__ dh,
                                                 u16* __restrict__ dl,
                                                 int Cin, int Cout) {
    int i = blockIdx.x * 256 + threadIdx.x;
    int total = Cout * Cin * 9;
    if (i >= total) return;
    int co = i / (Cin * 9);
    int r  = i - co * (Cin * 9);
    int ci = r / 9;
    int t  = r - ci * 9;          // t = ky*3+kx
    float w = src[i];
    u16 h = f2bf(w);
    float hf = __uint_as_float((u32)h << 16);
    u16 l = f2bf(w - hf);
    size_t di = ((size_t)t * Cout + co) * Cin + ci;
    dh[di] = h;
    dl[di] = l;
}

__global__ void h2zero_k(const float* __restrict__ t1, const float* __restrict__ w2,
                         const float* __restrict__ s2, const float* __restrict__ t2,
                         float* __restrict__ h2z) {
    int co = threadIdx.x;  // 64 threads
    float acc = 0.f;
    for (int j = 0; j < 32; j++) {
        float h1 = fmaxf(t1[j], 0.f);
        acc += h1 * w2[j * 64 + co];
    }
    h2z[co] = fmaxf(acc * s2[co] + t2[co], 0.f);
}

// ---- point stage ----------------------------------------------------------

__global__ __launch_bounds__(256) void count_pts(const float4* __restrict__ pts, int n,
                                                 int* __restrict__ cnt,
                                                 int* __restrict__ cellof) {
    int i = blockIdx.x * 256 + threadIdx.x;
    if (i >= n) return;
    float4 p = pts[i];
    int cell = -1;
    if (p.x >= -51.2f && p.x < 51.2f && p.y >= -51.2f && p.y < 51.2f) {
        // IEEE division to match reference floor((x - X_MIN)/X_RES) exactly.
        float qx = (p.x + 51.2f) / 0.4f;
        float qy = (p.y + 51.2f) / 0.4f;
        int xi = (int)floorf(qx); xi = xi < 0 ? 0 : (xi > 255 ? 255 : xi);
        int yi = (int)floorf(qy); yi = yi < 0 ? 0 : (yi > 255 ? 255 : yi);
        cell = yi * NXG + xi;
        atomicAdd(&cnt[cell], 1);
    }
    cellof[i] = cell;
}

__global__ __launch_bounds__(256) void scan1(const int* __restrict__ cnt,
                                             int* __restrict__ scnt,
                                             int* __restrict__ bsum,
                                             int* __restrict__ cur) {
    __shared__ int sm[256];
    int b = blockIdx.x, t = threadIdx.x;
    int v = cnt[b * 256 + t];
    sm[t] = v;
    __syncthreads();
    for (int off = 1; off < 256; off <<= 1) {
        int x = (t >= off) ? sm[t - off] : 0;
        __syncthreads();
        sm[t] += x;
        __syncthreads();
    }
    scnt[b * 256 + t] = sm[t] - v;       // exclusive
    if (t == 255) bsum[b] = sm[t];
    cur[b * 256 + t] = 0;
}

__global__ __launch_bounds__(256) void scan2(const int* __restrict__ bsum,
                                             int* __restrict__ boff,
                                             int* __restrict__ dT) {
    __shared__ int sm[256];
    int t = threadIdx.x;
    int v = bsum[t];
    sm[t] = v;
    __syncthreads();
    for (int off = 1; off < 256; off <<= 1) {
        int x = (t >= off) ? sm[t - off] : 0;
        __syncthreads();
        sm[t] += x;
        __syncthreads();
    }
    boff[t] = sm[t] - v;                 // exclusive
    if (t == 255) dT[0] = sm[t];
}

__global__ __launch_bounds__(256) void place_pts(const float4* __restrict__ pts, int n,
                                                 const int* __restrict__ cellof,
                                                 const int* __restrict__ scnt,
                                                 const int* __restrict__ boff,
                                                 int* __restrict__ cur,
                                                 float* __restrict__ fcomp) {
    int i = blockIdx.x * 256 + threadIdx.x;
    if (i >= n) return;
    int cell = cellof[i];
    if (cell < 0) return;
    int slot = atomicAdd(&cur[cell], 1);
    if (slot >= 32) return;  // P(cell>32 pts) ~ 1e-30 at lambda~2.6
    int pos = boff[cell >> 8] + scnt[cell] + slot;
    float4 p = pts[i];
    int xi = cell & 255, yi = cell >> 8;
    float cx = (float)xi * 0.4f + -51.0f;
    float cy = (float)yi * 0.4f + -51.0f;
    float4* d = (float4*)(fcomp + (size_t)pos * 8);
    d[0] = make_float4(p.x, p.y, p.z, p.w);
    d[1] = make_float4(p.x - cx, p.y - cy, p.z, 0.f);
}

__global__ __launch_bounds__(256) void mlp_pts(
    const float* __restrict__ fcomp, const int* __restrict__ dT,
    const float* __restrict__ w1, const float* __restrict__ s1, const float* __restrict__ t1,
    const float* __restrict__ w2, const float* __restrict__ s2, const float* __restrict__ t2,
    float* __restrict__ hcomp) {
    int i = blockIdx.x * 256 + threadIdx.x;
    if (i >= dT[0]) return;
    const float4* f = (const float4*)(fcomp + (size_t)i * 8);
    float4 a = f[0], b = f[1];
    float h1[32];
#pragma unroll
    for (int k = 0; k < 32; k++) {
        float v = a.x * w1[0 * 32 + k] + a.y * w1[1 * 32 + k] + a.z * w1[2 * 32 + k]
                + a.w * w1[3 * 32 + k] + b.x * w1[4 * 32 + k] + b.y * w1[5 * 32 + k]
                + b.z * w1[6 * 32 + k];
        h1[k] = fmaxf(v * s1[k] + t1[k], 0.f);
    }
    float acc[64];
#pragma unroll
    for (int c = 0; c < 64; c++) acc[c] = 0.f;
#pragma unroll
    for (int k = 0; k < 32; k++) {
        float hk = h1[k];
#pragma unroll
        for (int c4 = 0; c4 < 16; c4++) {
            float4 wv = *(const float4*)&w2[k * 64 + c4 * 4];
            acc[c4 * 4 + 0] += hk * wv.x;
            acc[c4 * 4 + 1] += hk * wv.y;
            acc[c4 * 4 + 2] += hk * wv.z;
            acc[c4 * 4 + 3] += hk * wv.w;
        }
    }
    float* o = hcomp + (size_t)i * 64;
#pragma unroll
    for (int c4 = 0; c4 < 16; c4++) {
        float4 ov;
        ov.x = fmaxf(acc[c4 * 4 + 0] * s2[c4 * 4 + 0] + t2[c4 * 4 + 0], 0.f);
        ov.y = fmaxf(acc[c4 * 4 + 1] * s2[c4 * 4 + 1] + t2[c4 * 4 + 1], 0.f);
        ov.z = fmaxf(acc[c4 * 4 + 2] * s2[c4 * 4 + 2] + t2[c4 * 4 + 2], 0.f);
        ov.w = fmaxf(acc[c4 * 4 + 3] * s2[c4 * 4 + 3] + t2[c4 * 4 + 3], 0.f);
        *(float4*)&o[c4 * 4] = ov;
    }
}

// Wave per cell; writes bf16 hi/lo planes feeding conv1a.
__global__ __launch_bounds__(256) void cell_reduce(
    const int* __restrict__ cnt, const int* __restrict__ scnt,
    const int* __restrict__ boff, const float* __restrict__ hcomp,
    const float* __restrict__ h2z, u16* __restrict__ deschi, u16* __restrict__ desclo) {
    int cell = blockIdx.x * 4 + (threadIdx.x >> 6);
    int co = threadIdx.x & 63;
    int c = cnt[cell];
    int start = boff[cell >> 8] + scnt[cell];
    int cc = c < 32 ? c : 32;
    float m = (c > 0 && c < 32) ? h2z[co] : 0.f;
    const float* hp = hcomp + (size_t)start * 64 + co;
    for (int s = 0; s < cc; s++) m = fmaxf(m, hp[(size_t)s * 64]);
    u16 h = f2bf(m);
    float hf = __uint_as_float((u32)h << 16);
    u16 l = f2bf(m - hf);
    deschi[(size_t)cell * 64 + co] = h;
    desclo[(size_t)cell * 64 + co] = l;
}

// ---- MFMA conv ------------------------------------------------------------
// Implicit GEMM: D[pix][co] = sum_{t,ci} A[pix+shift(t)][ci] * W[t][co][ci].
// Block: 256 thr / 4 waves; pixel tile 16 x TY; co tile 64 (blockIdx.z).
// Wave: MT=TY/4 m-tiles (one 16-pixel y-row each) x 4 n-tiles (16 co each).
// A hi/lo staged in LDS per 32-ci chunk (halo 18 x (TY+2)); B hi/lo read
// from global (all 4 waves identical addresses -> L1). 3 MFMA per tile pair.
// Fragment maps (16x16x32 bf16): A row=lane&15, k=(lane>>4)*8+j;
// B col=lane&15, k=(lane>>4)*8+j; D col=lane&15, row=(lane>>4)*4+reg [m89].
template <int CIN, int COUT, int TY, bool WF32>
__global__ __launch_bounds__(256) void conv3x3_mfma(
    const u16* __restrict__ inh, const u16* __restrict__ inl,
    const u16* __restrict__ wh, const u16* __restrict__ wl,
    const float* __restrict__ bs, const float* __restrict__ bt,
    u16* __restrict__ outh, u16* __restrict__ outl, float* __restrict__ outf) {
    constexpr int MT = TY / 4;
    constexpr int HP = (TY + 2) * 18;     // halo pixels
    __shared__ u16 Ah[HP * 32];
    __shared__ u16 Al[HP * 32];

    const int tid = threadIdx.x;
    const int lane = tid & 63, wid = tid >> 6;
    const int bx = blockIdx.x, by = blockIdx.y;
    const int cob = blockIdx.z * 64;

    fx4 acc[MT][4];
#pragma unroll
    for (int mt = 0; mt < MT; mt++)
#pragma unroll
        for (int nt = 0; nt < 4; nt++) acc[mt][nt] = (fx4){0.f, 0.f, 0.f, 0.f};

    const int ax = lane & 15, akg = (lane >> 4) * 8;

#pragma unroll 1
    for (int cc = 0; cc < CIN / 32; ++cc) {
        if (cc) __syncthreads();
        // stage halo tile (hi+lo), 16B chunks; LDS writes are linear per wave
        for (int i = tid; i < HP * 4; i += 256) {
            int p = i >> 2, c = i & 3;
            int ty = p / 18, tx = p - ty * 18;
            int gy = by * TY + ty - 1, gx = bx * 16 + tx - 1;
            ux4 vh = (ux4){0u, 0u, 0u, 0u}, vl = vh;
            if (gy >= 0 && gy < NYG && gx >= 0 && gx < NXG) {
                size_t gi = ((size_t)(gy * NXG + gx)) * CIN + cc * 32 + c * 8;
                vh = *(const ux4*)&inh[gi];
                vl = *(const ux4*)&inl[gi];
            }
            *(ux4*)&Ah[p * 32 + c * 8] = vh;
            *(ux4*)&Al[p * 32 + c * 8] = vl;
        }
        __syncthreads();

#pragma unroll
        for (int t = 0; t < 9; ++t) {
            const int ky = t / 3, kx = t - (t / 3) * 3;
            // B frags from global (L1-hot: shared by all 4 waves)
            const u16* wbh = wh + ((size_t)(t * COUT + cob)) * CIN + cc * 32;
            const u16* wbl = wl + ((size_t)(t * COUT + cob)) * CIN + cc * 32;
            sx8 bh[4], bl[4];
#pragma unroll
            for (int nt = 0; nt < 4; nt++) {
                size_t off = (size_t)(nt * 16 + ax) * CIN + akg;
                bh[nt] = *(const sx8*)&wbh[off];
                bl[nt] = *(const sx8*)&wbl[off];
            }
            // A frags from LDS
            sx8 ah[MT], al[MT];
#pragma unroll
            for (int mt = 0; mt < MT; mt++) {
                int prow = (wid * MT + mt + ky) * 18 + kx;
                int aoff = (prow + ax) * 32 + akg;
                ah[mt] = *(const sx8*)&Ah[aoff];
                al[mt] = *(const sx8*)&Al[aoff];
            }
#pragma unroll
            for (int mt = 0; mt < MT; mt++)
#pragma unroll
                for (int nt = 0; nt < 4; nt++) {
                    acc[mt][nt] = __builtin_amdgcn_mfma_f32_16x16x32_bf16(
                        al[mt], bh[nt], acc[mt][nt], 0, 0, 0);
                    acc[mt][nt] = __builtin_amdgcn_mfma_f32_16x16x32_bf16(
                        ah[mt], bl[nt], acc[mt][nt], 0, 0, 0);
                    acc[mt][nt] = __builtin_amdgcn_mfma_f32_16x16x32_bf16(
                        ah[mt], bh[nt], acc[mt][nt], 0, 0, 0);
                }
        }
    }

    // epilogue: D col(lane&15)=co-offset, row((lane>>4)*4+r)=x
    const int ex = (lane >> 4) * 4, eco = lane & 15;
#pragma unroll
    for (int mt = 0; mt < MT; mt++) {
        int y = by * TY + wid * MT + mt;
#pragma unroll
        for (int nt = 0; nt < 4; nt++) {
            int co = cob + nt * 16 + eco;
            float s = bs[co], b = bt[co];
#pragma unroll
            for (int r = 0; r < 4; r++) {
                int x = bx * 16 + ex + r;
                float v = fmaxf(acc[mt][nt][r] * s + b, 0.f);
                size_t pix = (size_t)y * NXG + x;
                if (WF32) {
                    outf[pix * COUT + co] = v;
                } else {
                    u16 h = f2bf(v);
                    float hf = __uint_as_float((u32)h << 16);
                    u16 l = f2bf(v - hf);
                    outh[pix * COUT + co] = h;
                    outl[pix * COUT + co] = l;
                }
            }
        }
    }
}

// fp32 NHWC [65536][64] -> NCHW [64][65536]
__global__ __launch_bounds__(256) void nhwc_to_nchw(const float* __restrict__ in,
                                                    float* __restrict__ out) {
    __shared__ float tl[64][65];
    int bp = blockIdx.x * 64;
    int t = threadIdx.x;
    int p = t >> 2, q = t & 3;
#pragma unroll
    for (int j = 0; j < 4; j++) {
        float4 v = *(const float4*)&in[(size_t)(bp + p) * 64 + q * 16 + j * 4];
        tl[p][q * 16 + j * 4 + 0] = v.x;
        tl[p][q * 16 + j * 4 + 1] = v.y;
        tl[p][q * 16 + j * 4 + 2] = v.z;
        tl[p][q * 16 + j * 4 + 3] = v.w;
    }
    __syncthreads();
    int co = t >> 2;
#pragma unroll
    for (int j = 0; j < 4; j++) {
        int pp = q * 16 + j * 4;
        float4 v = make_float4(tl[pp][co], tl[pp + 1][co], tl[pp + 2][co], tl[pp + 3][co]);
        *(float4*)&out[(size_t)co * 65536 + bp + pp] = v;
    }
}

extern "C" void kernel_launch(void* const* d_in, const int* in_sizes, int n_in,
                              void* d_out, int out_size, void* d_ws, size_t ws_size,
                              hipStream_t stream) {
    const float* points = (const float*)d_in[0];
    const float* w1 = (const float*)d_in[1];
    const float* s1 = (const float*)d_in[2];
    const float* t1 = (const float*)d_in[3];
    const float* w2 = (const float*)d_in[4];
    const float* s2 = (const float*)d_in[5];
    const float* t2 = (const float*)d_in[6];
    const float* cw1a = (const float*)d_in[7];
    const float* cs1a = (const float*)d_in[8];
    const float* ct1a = (const float*)d_in[9];
    const float* cw1b = (const float*)d_in[10];
    const float* cs1b = (const float*)d_in[11];
    const float* ct1b = (const float*)d_in[12];
    const float* cw2a = (const float*)d_in[13];
    const float* cs2a = (const float*)d_in[14];
    const float* ct2a = (const float*)d_in[15];
    const float* cw2b = (const float*)d_in[16];
    const float* cs2b = (const float*)d_in[17];
    const float* ct2b = (const float*)d_in[18];
    int n = in_sizes[0] / 4;

    // Workspace (max 91.2 MB; 98 MB proven OK in R2):
    //  <2M   small: cnt/scnt/cur/boff/dT/h2z/cellof/bsum
    //  2M    bf16 weights (1.27 MB)
    //  4M    fcomp 6.4M [dead after mlp_pts]
    //  12M   deschi 8M | 20M desclo 8M [dead after conv1a]
    //  40M   hcomp 51.2M [dead after cell_reduce]
    //  40M   X1h 16M | 56M X1l 16M (conv1a out) [alias hcomp; dead after conv1b]
    //  4M    X2h 16M | 20M X2l 16M (conv1b out) [alias fcomp+desc; dead after conv2a]
    //  72M   X3h 8M  | 80M X3l 8M  (conv2a out) [dead after conv2b]
    //  40M   X4 16M fp32 NHWC (conv2b out) [alias X1]
    char* ws = (char*)d_ws;
    int*   cnt    = (int*)(ws + 0);
    int*   scnt   = (int*)(ws + 262144);
    int*   cur    = (int*)(ws + 524288);
    int*   boff   = (int*)(ws + 786432);
    int*   dT     = (int*)(ws + 790528);
    float* h2z    = (float*)(ws + 794624);
    int*   cellof = (int*)(ws + (1ull << 20));
    int*   bsum   = (int*)(ws + (1ull << 20) + 819200);
    size_t W0 = 2ull << 20;
    u16* w1ah = (u16*)(ws + W0 + 0);
    u16* w1al = (u16*)(ws + W0 + 147456);
    u16* w1bh = (u16*)(ws + W0 + 294912);
    u16* w1bl = (u16*)(ws + W0 + 589824);
    u16* w2ah = (u16*)(ws + W0 + 884736);
    u16* w2al = (u16*)(ws + W0 + 1032192);
    u16* w2bh = (u16*)(ws + W0 + 1179648);
    u16* w2bl = (u16*)(ws + W0 + 1253376);
    float* fcomp  = (float*)(ws + (4ull << 20));
    u16*   deschi = (u16*)(ws + (12ull << 20));
    u16*   desclo = (u16*)(ws + (20ull << 20));
    float* hcomp  = (float*)(ws + (40ull << 20));
    u16*   X1h    = (u16*)(ws + (40ull << 20));
    u16*   X1l    = (u16*)(ws + (56ull << 20));
    u16*   X2h    = (u16*)(ws + (4ull << 20));
    u16*   X2l    = (u16*)(ws + (20ull << 20));
    u16*   X3h    = (u16*)(ws + (72ull << 20));
    u16*   X3l    = (u16*)(ws + (80ull << 20));
    float* X4     = (float*)(ws + (40ull << 20));

    hipMemsetAsync(cnt, 0, 262144, stream);

    repack_wb<<<(128 * 64 * 9 + 255) / 256, 256, 0, stream>>>(cw1a, w1ah, w1al, 64, 128);
    repack_wb<<<(128 * 128 * 9 + 255) / 256, 256, 0, stream>>>(cw1b, w1bh, w1bl, 128, 128);
    repack_wb<<<(64 * 128 * 9 + 255) / 256, 256, 0, stream>>>(cw2a, w2ah, w2al, 128, 64);
    repack_wb<<<(64 * 64 * 9 + 255) / 256, 256, 0, stream>>>(cw2b, w2bh, w2bl, 64, 64);
    h2zero_k<<<1, 64, 0, stream>>>(t1, w2, s2, t2, h2z);

    count_pts<<<(n + 255) / 256, 256, 0, stream>>>((const float4*)points, n, cnt, cellof);
    scan1<<<256, 256, 0, stream>>>(cnt, scnt, bsum, cur);
    scan2<<<1, 256, 0, stream>>>(bsum, boff, dT);
    place_pts<<<(n + 255) / 256, 256, 0, stream>>>((const float4*)points, n, cellof,
                                                   scnt, boff, cur, fcomp);
    mlp_pts<<<(n + 255) / 256, 256, 0, stream>>>(fcomp, dT, w1, s1, t1, w2, s2, t2, hcomp);
    cell_reduce<<<65536 / 4, 256, 0, stream>>>(cnt, scnt, boff, hcomp, h2z, deschi, desclo);

    conv3x3_mfma<64, 128, 16, false><<<dim3(16, 16, 2), 256, 0, stream>>>(
        deschi, desclo, w1ah, w1al, cs1a, ct1a, X1h, X1l, nullptr);
    conv3x3_mfma<128, 128, 16, false><<<dim3(16, 16, 2), 256, 0, stream>>>(
        X1h, X1l, w1bh, w1bl, cs1b, ct1b, X2h, X2l, nullptr);
    conv3x3_mfma<128, 64, 8, false><<<dim3(16, 32, 1), 256, 0, stream>>>(
        X2h, X2l, w2ah, w2al, cs2a, ct2a, X3h, X3l, nullptr);
    conv3x3_mfma<64, 64, 8, true><<<dim3(16, 32, 1), 256, 0, stream>>>(
        X3h, X3l, w2bh, w2bl, cs2b, ct2b, nullptr, nullptr, X4);
    nhwc_to_nchw<<<1024, 256, 0, stream>>>(X4, (float*)d_out);
}